// Round 10
// baseline (939.459 us; speedup 1.0000x reference)
//
#include <hip/hip_runtime.h>
#include <hip/hip_bf16.h>
#include <math.h>

#define Bsz 1024
#define Nn  11
#define Ff  512
#define Zi  10
#define G3  1536

#define PSH  528    // h1 plane stride (32 rows * 16B + 16 pad)
#define PLA  1056   // gates A plane stride (64 rows * 16B + 32 pad)
#define PGW2 2080   // gates W plane stride (128 g * 16B + 32 pad)

typedef __attribute__((ext_vector_type(8))) short bfrag;
typedef __attribute__((ext_vector_type(16))) float f32x16;

__device__ __forceinline__ unsigned f2bf(float f) {
    __hip_bfloat16 h = __float2bfloat16(f);
    return (unsigned)*reinterpret_cast<unsigned short*>(&h);
}
__device__ __forceinline__ uint4 pack8(float v0, float v1, float v2, float v3,
                                       float v4, float v5, float v6, float v7) {
    uint4 pk;
    pk.x = f2bf(v0) | (f2bf(v1) << 16);
    pk.y = f2bf(v2) | (f2bf(v3) << 16);
    pk.z = f2bf(v4) | (f2bf(v5) << 16);
    pk.w = f2bf(v6) | (f2bf(v7) << 16);
    return pk;
}
__device__ __forceinline__ void pair_decode(int mode, int p, int& pi, int& pj) {
    if (mode == 0) { int r = p, i = 0; while (r >= Nn - i) { r -= Nn - i; ++i; } pi = i; pj = i + r; }
    else { pi = p; pj = Zi; }
}
// async global->LDS, 16B/lane; dst is wave-uniform base (+lane*16 by HW);
// src IS per-lane.
__device__ __forceinline__ void gl_lds16(const void* src, void* dst) {
    __builtin_amdgcn_global_load_lds((const __attribute__((address_space(1))) void*)src,
                                     (__attribute__((address_space(3))) void*)dst, 16, 0, 0);
}

// ---------------------------------------------------------------------------
__global__ void init_col_kernel(const float* __restrict__ nf, float* __restrict__ col) {
    int idx = blockIdx.x * 256 + threadIdx.x;
    int b = idx >> 9, f = idx & 511;
    col[idx] = nf[(b * Nn + Zi) * Ff + f];
}

__global__ void convert_bf16_kernel(const float* __restrict__ src,
                                    unsigned short* __restrict__ dst) {
    int i = blockIdx.x * 256 + threadIdx.x;
    dst[i] = (unsigned short)f2bf(src[i]);
}

// ---------------------------------------------------------------------------
// Fused link MLP, 2 blocks/CU. Block = 32 rows (1 pair x 32 batches) x 512 cols.
// 512 thr / 8 waves; wave tile 32x64 (acc0+acc1 = 32 VGPR). K_STEP = 16.
// W: 16KB K-slice dbuf staged via global_load_lds (no staging VGPRs).
// A (E): 1KB tile dbuf, built by wave 0 (loads at step-top, write post-MFMA).
// h1: resident 33KB, written once at the layer boundary, is layer-2's A.
// One barrier per step; cross-block overlap (2/CU) hides the vmcnt drain.
// ---------------------------------------------------------------------------
__global__ __launch_bounds__(512, 4) void link_kernel(
    const float* __restrict__ nf, const float* __restrict__ colp,
    const unsigned short* __restrict__ W1bf, const float* __restrict__ b1,
    const unsigned short* __restrict__ W2bf, const float* __restrict__ b2,
    const float* __restrict__ w_out, const float* __restrict__ b_out,
    float* __restrict__ adj, int mode)
{
    __shared__ char  Wb[2][2 * 8192];   // 32,768 B: [buf][kq-plane][g*16B]
    __shared__ char  H1[64 * PSH];      // 33,792 B: [col-plane(8)][row*16B]
    __shared__ char  Ab[2][2 * 512];    //  2,048 B: [buf][kq-plane][row*16B]
    __shared__ float Pl[8][32];         //  1,024 B

    const int tid = threadIdx.x;
    const int pr  = blockIdx.x >> 5;
    const int bc  = blockIdx.x & 31;
    int pi, pj; pair_decode(mode, pr, pi, pj);

    const int wid = tid >> 6;
    const int l   = tid & 63;
    const int lr  = l & 31;
    const int kg  = l >> 5;

    // producer thread setup (wave 0 builds A-tiles for layer 1)
    const bool prod = (tid < 64);
    const int  arow = tid & 31;          // E row
    const int  akq  = (tid >> 5) & 1;    // k-octet within step
    const float* xi = nullptr; const float* xj = nullptr;
    if (prod) {
        int b = bc * 32 + arow;
        xi = (pi == Zi) ? (colp + b * Ff) : (nf + (b * Nn + pi) * Ff);
        xj = (pj == Zi) ? (colp + b * Ff) : (nf + (b * Nn + pj) * Ff);
    }

    // ---- stage W1 slice 0 (async) ----
#pragma unroll
    for (int i = 0; i < 2; ++i) {
        int cb = i * 512 + wid * 64;               // wave-uniform chunk base
        int g  = (cb & 511) + l;                    // per-lane col
        gl_lds16(W1bf + g * Ff + i * 8, (char*)Wb[0] + cb * 16);
    }
    // ---- build A-tile 0 ----
    if (prod) {
        const float* pxi = xi + akq * 8;
        const float* pxj = xj + akq * 8;
        float4 u0 = *(const float4*)pxi, u1 = *(const float4*)(pxi + 4);
        float4 v0 = *(const float4*)pxj, v1 = *(const float4*)(pxj + 4);
        *(uint4*)(&Ab[0][akq * 512 + arow * 16]) =
            pack8(u0.x*v0.x, u0.y*v0.y, u0.z*v0.z, u0.w*v0.w,
                  u1.x*v1.x, u1.y*v1.y, u1.z*v1.z, u1.w*v1.w);
    }
    __syncthreads();

    f32x16 acc0 = (f32x16)(0.f), acc1 = (f32x16)(0.f);
    const int c0 = wid * 64 + lr;
    const int c1 = c0 + 32;

#pragma unroll 1
    for (int gks = 0; gks < 64; ++gks) {
        const int cur = gks & 1;

        // issue next W slice (async, no regs)
        if (gks < 63) {
            const unsigned short* Ws = (gks >= 31) ? W2bf : W1bf;
            const int k0 = ((gks + 1) & 31) * 16;
#pragma unroll
            for (int i = 0; i < 2; ++i) {
                int cb = i * 512 + wid * 64;
                int g  = (cb & 511) + l;
                gl_lds16(Ws + g * Ff + k0 + i * 8, (char*)Wb[cur ^ 1] + cb * 16);
            }
        }
        // issue next A-tile loads (layer 1 only)
        float4 u0, u1, v0, v1;
        const bool doA = prod && (gks + 1 < 32);
        if (doA) {
            const int kt = (gks + 1) * 16 + akq * 8;
            u0 = *(const float4*)(xi + kt); u1 = *(const float4*)(xi + kt + 4);
            v0 = *(const float4*)(xj + kt); v1 = *(const float4*)(xj + kt + 4);
        }

        // MFMA for this step
        {
            bfrag a;
            if (gks < 32) a = *(const bfrag*)(&Ab[cur][kg * 512 + lr * 16]);
            else {
                const int ks = gks & 31;
                a = *(const bfrag*)(&H1[(2 * ks + kg) * PSH + lr * 16]);
            }
            const char* Wc = (const char*)Wb[cur];
            bfrag w0 = *(const bfrag*)(Wc + kg * 8192 + c0 * 16);
            bfrag w1 = *(const bfrag*)(Wc + kg * 8192 + c1 * 16);
            acc0 = __builtin_amdgcn_mfma_f32_32x32x16_bf16(a, w0, acc0, 0, 0, 0);
            acc1 = __builtin_amdgcn_mfma_f32_32x32x16_bf16(a, w1, acc1, 0, 0, 0);
        }

        // write next A-tile (loads have drained under the MFMAs)
        if (doA) {
            *(uint4*)(&Ab[cur ^ 1][akq * 512 + arow * 16]) =
                pack8(u0.x*v0.x, u0.y*v0.y, u0.z*v0.z, u0.w*v0.w,
                      u1.x*v1.x, u1.y*v1.y, u1.z*v1.z, u1.w*v1.w);
        }

        // layer boundary: h1 = relu(acc + b1) -> H1 planes; re-zero acc
        if (gks == 31) {
            float bv0 = b1[c0], bv1 = b1[c1];
#pragma unroll
            for (int reg = 0; reg < 16; ++reg) {
                int row = (reg & 3) + 8 * (reg >> 2) + 4 * kg;
                float v0h = fmaxf(acc0[reg] + bv0, 0.f);
                float v1h = fmaxf(acc1[reg] + bv1, 0.f);
                *(unsigned short*)(&H1[(c0 >> 3) * PSH + row * 16 + (c0 & 7) * 2]) =
                    (unsigned short)f2bf(v0h);
                *(unsigned short*)(&H1[(c1 >> 3) * PSH + row * 16 + (c1 & 7) * 2]) =
                    (unsigned short)f2bf(v1h);
            }
            acc0 = (f32x16)(0.f);
            acc1 = (f32x16)(0.f);
        }

        __syncthreads();   // drains next-slice stage + publishes A/h1 writes
    }

    // ---- fused layer-3: rowsum of relu(acc+b2)*w_out ----
    {
        float bv0 = b2[c0], bv1 = b2[c1];
        float wv0 = w_out[c0], wv1 = w_out[c1];
        float rs[16];
#pragma unroll
        for (int reg = 0; reg < 16; ++reg)
            rs[reg] = fmaxf(acc0[reg] + bv0, 0.f) * wv0
                    + fmaxf(acc1[reg] + bv1, 0.f) * wv1;
#pragma unroll
        for (int off = 1; off < 32; off <<= 1)
#pragma unroll
            for (int reg = 0; reg < 16; ++reg)
                rs[reg] += __shfl_xor(rs[reg], off);
        if (lr == 0) {
#pragma unroll
            for (int reg = 0; reg < 16; ++reg) {
                int row = (reg & 3) + 8 * (reg >> 2) + 4 * kg;
                Pl[wid][row] = rs[reg];
            }
        }
    }
    __syncthreads();
    if (tid < 32) {
        float v = b_out[0];
#pragma unroll
        for (int w = 0; w < 8; ++w) v += Pl[w][tid];
        int b = bc * 32 + tid;
        adj[b * (Nn * Nn) + pi * Nn + pj] = v;
        if (pi != pj) adj[b * (Nn * Nn) + pj * Nn + pi] = v;
    }
}

// ---------------------------------------------------------------------------
__global__ void softmax_az_kernel(const float* __restrict__ adj, float* __restrict__ a_z) {
    int b = blockIdx.x * 256 + threadIdx.x;
    if (b >= Bsz) return;
    const float* row = adj + b * (Nn * Nn) + Zi * Nn;
    float mx = row[0];
#pragma unroll
    for (int j = 1; j < Nn; ++j) mx = fmaxf(mx, row[j]);
    float e[Nn]; float s = 0.f;
#pragma unroll
    for (int j = 0; j < Nn; ++j) { e[j] = expf(row[j] - mx); s += e[j]; }
    float inv = 1.f / s;
#pragma unroll
    for (int j = 0; j < Nn; ++j) a_z[b * Nn + j] = e[j] * inv;
}

__global__ void mfix_kernel(const float* __restrict__ nf, const float* __restrict__ a_z,
                            float* __restrict__ m_fix) {
    int idx = blockIdx.x * 256 + threadIdx.x;
    int b = idx >> 9, f = idx & 511;
    float s = 0.f;
#pragma unroll
    for (int j = 0; j < Nn - 1; ++j)
        s += a_z[b * Nn + j] * nf[(b * Nn + j) * Ff + f];
    m_fix[idx] = s;
}

// ---------------------------------------------------------------------------
// gates: gi = (m_fix + az*col) @ Wih^T ; gh = col @ Whh^T (fp32 out)
// ---------------------------------------------------------------------------
__global__ __launch_bounds__(256, 3) void gates_kernel(
    const float* __restrict__ m_fix, const float* __restrict__ a_z,
    const float* __restrict__ colp,
    const unsigned short* __restrict__ Wih, const unsigned short* __restrict__ Whh,
    float* __restrict__ gi, float* __restrict__ gh)
{
    __shared__ char Wb[2][4 * PGW2];
    __shared__ char Ab[2][4 * PLA];

    const int xb = blockIdx.x, bc = blockIdx.y, tid = threadIdx.x;
    const bool isGi = xb < 12;
    const int nbase = (isGi ? xb : xb - 12) * 128;
    const unsigned short* W = isGi ? Wih : Whh;
    float* C = isGi ? gi : gh;

    const int bloc = tid >> 2;
    const int kc   = tid & 3;
    const int b    = bc * 64 + bloc;
    const float* cs = colp + b * Ff;
    const float* mf = m_fix + b * Ff;
    const float azv = isGi ? a_z[b * Nn + Zi] : 0.f;

    uint4 wreg[2];
    uint4 areg;

    auto loadA = [&](int k0) {
        const float* pc = cs + k0 + kc * 8;
        float4 c0 = *(const float4*)pc, c1 = *(const float4*)(pc + 4);
        if (isGi) {
            const float* pm = mf + k0 + kc * 8;
            float4 m0 = *(const float4*)pm, m1 = *(const float4*)(pm + 4);
            areg = pack8(m0.x + azv*c0.x, m0.y + azv*c0.y, m0.z + azv*c0.z, m0.w + azv*c0.w,
                         m1.x + azv*c1.x, m1.y + azv*c1.y, m1.z + azv*c1.z, m1.w + azv*c1.w);
        } else {
            areg = pack8(c0.x, c0.y, c0.z, c0.w, c1.x, c1.y, c1.z, c1.w);
        }
    };

    loadA(0);
#pragma unroll
    for (int i = 0; i < 2; ++i) {
        int chunk = i * 256 + tid;
        wreg[i] = *(const uint4*)(W + (nbase + (chunk >> 2)) * Ff + (chunk & 3) * 8);
    }
#pragma unroll
    for (int i = 0; i < 2; ++i) {
        int chunk = i * 256 + tid;
        *(uint4*)(&Wb[0][(chunk & 3) * PGW2 + (chunk >> 2) * 16]) = wreg[i];
    }
    *(uint4*)(&Ab[0][kc * PLA + bloc * 16]) = areg;
    __syncthreads();

    const int l  = tid & 63;
    const int nw = tid >> 6;
    const int lr = l & 31;
    const int kg = l >> 5;

    f32x16 acc[2];
    acc[0] = (f32x16)(0.f);
    acc[1] = (f32x16)(0.f);

#pragma unroll 1
    for (int ks = 0; ks < 16; ++ks) {
        const int cur = ks & 1;
        if (ks < 15) {
            const int k0 = (ks + 1) * 32;
            loadA(k0);
#pragma unroll
            for (int i = 0; i < 2; ++i) {
                int chunk = i * 256 + tid;
                wreg[i] = *(const uint4*)(W + (nbase + (chunk >> 2)) * Ff + k0 + (chunk & 3) * 8);
            }
        }
#pragma unroll
        for (int s = 0; s < 2; ++s) {
            const int kcv = 2 * s + kg;
            bfrag a0 = *(const bfrag*)(&Ab[cur][kcv * PLA + lr * 16]);
            bfrag a1 = *(const bfrag*)(&Ab[cur][kcv * PLA + (32 + lr) * 16]);
            bfrag bf = *(const bfrag*)(&Wb[cur][kcv * PGW2 + (nw * 32 + lr) * 16]);
            acc[0] = __builtin_amdgcn_mfma_f32_32x32x16_bf16(a0, bf, acc[0], 0, 0, 0);
            acc[1] = __builtin_amdgcn_mfma_f32_32x32x16_bf16(a1, bf, acc[1], 0, 0, 0);
        }
        if (ks < 15) {
#pragma unroll
            for (int i = 0; i < 2; ++i) {
                int chunk = i * 256 + tid;
                *(uint4*)(&Wb[cur ^ 1][(chunk & 3) * PGW2 + (chunk >> 2) * 16]) = wreg[i];
            }
            *(uint4*)(&Ab[cur ^ 1][kc * PLA + bloc * 16]) = areg;
        }
        __syncthreads();
    }

    const int colg = nbase + nw * 32 + lr;
#pragma unroll
    for (int m = 0; m < 2; ++m) {
#pragma unroll
        for (int reg = 0; reg < 16; ++reg) {
            int row = m * 32 + (reg & 3) + 8 * (reg >> 2) + 4 * kg;
            C[(bc * 64 + row) * G3 + colg] = acc[m][reg];
        }
    }
}

// ---------------------------------------------------------------------------
__global__ void gru_kernel(const float* __restrict__ gi, const float* __restrict__ gh,
                           float* __restrict__ col) {
    int idx = blockIdx.x * 256 + threadIdx.x;   // 4 f per thread
    int b = idx >> 7, f = (idx & 127) * 4;
    const float* gib = gi + b * G3;
    const float* ghb = gh + b * G3;
    float4 ir = *(const float4*)(gib + f);
    float4 iz = *(const float4*)(gib + Ff + f);
    float4 in = *(const float4*)(gib + 2 * Ff + f);
    float4 hr = *(const float4*)(ghb + f);
    float4 hz = *(const float4*)(ghb + Ff + f);
    float4 hn = *(const float4*)(ghb + 2 * Ff + f);
    float4 h  = *(const float4*)(col + b * Ff + f);
    float4 o;
#define GRU1(c) { \
    float r = 1.f / (1.f + expf(-(ir.c + hr.c))); \
    float z = 1.f / (1.f + expf(-(iz.c + hz.c))); \
    float n = tanhf(in.c + r * hn.c); \
    o.c = (1.f - z) * n + z * h.c; }
    GRU1(x) GRU1(y) GRU1(z) GRU1(w)
#undef GRU1
    *(float4*)(col + b * Ff + f) = o;
}

// ---------------------------------------------------------------------------
extern "C" void kernel_launch(void* const* d_in, const int* in_sizes, int n_in,
                              void* d_out, int out_size, void* d_ws, size_t ws_size,
                              hipStream_t stream) {
    const float* nf    = (const float*)d_in[0];
    const float* W1    = (const float*)d_in[1];
    const float* b1    = (const float*)d_in[2];
    const float* W2    = (const float*)d_in[3];
    const float* b2    = (const float*)d_in[4];
    const float* w_out = (const float*)d_in[5];
    const float* b_out = (const float*)d_in[6];
    const float* W_ih  = (const float*)d_in[7];
    const float* W_hh  = (const float*)d_in[8];

    float* adj = (float*)d_out;                 // (B, 11, 11)
    float* col = adj + Bsz * Nn * Nn;           // (B, 512)

    unsigned short* W1bf  = (unsigned short*)d_ws;
    unsigned short* W2bf  = W1bf + Ff * Ff;
    unsigned short* Wihbf = W2bf + Ff * Ff;
    unsigned short* Whhbf = Wihbf + G3 * Ff;
    float* a_z   = (float*)(Whhbf + G3 * Ff);
    float* m_fix = a_z + 16384;
    float* gi    = m_fix + Bsz * Ff;
    float* gh    = gi + Bsz * G3;

    init_col_kernel<<<(Bsz * Ff) / 256, 256, 0, stream>>>(nf, col);
    convert_bf16_kernel<<<(Ff * Ff) / 256, 256, 0, stream>>>(W1, W1bf);
    convert_bf16_kernel<<<(Ff * Ff) / 256, 256, 0, stream>>>(W2, W2bf);
    convert_bf16_kernel<<<(G3 * Ff) / 256, 256, 0, stream>>>(W_ih, Wihbf);
    convert_bf16_kernel<<<(G3 * Ff) / 256, 256, 0, stream>>>(W_hh, Whhbf);

    for (int t = 0; t < 3; ++t) {
        const int mode   = (t == 0) ? 0 : 1;
        const int npairs = (t == 0) ? 66 : 11;

        link_kernel<<<npairs * 32, 512, 0, stream>>>(nf, col, W1bf, b1, W2bf, b2,
                                                     w_out, b_out, adj, mode);
        softmax_az_kernel<<<Bsz / 256, 256, 0, stream>>>(adj, a_z);
        mfix_kernel<<<(Bsz * Ff) / 256, 256, 0, stream>>>(nf, a_z, m_fix);

        for (int s = 0; s < 3; ++s) {
            gates_kernel<<<dim3(24, 16), 256, 0, stream>>>(m_fix, a_z, col,
                                                           Wihbf, Whhbf, gi, gh);
            gru_kernel<<<(Bsz * Ff) / 4 / 256, 256, 0, stream>>>(gi, gh, col);
        }
    }
}

// Round 11
// 525.357 us; speedup vs baseline: 1.7882x; 1.7882x over previous
//
#include <hip/hip_runtime.h>
#include <hip/hip_bf16.h>
#include <math.h>

#define Bsz 1024
#define Nn  11
#define Ff  512
#define Zi  10
#define G3  1536

typedef __attribute__((ext_vector_type(8))) short bfrag;
typedef __attribute__((ext_vector_type(16))) float f32x16;

__device__ __forceinline__ unsigned f2bf(float f) {
    __hip_bfloat16 h = __float2bfloat16(f);
    return (unsigned)*reinterpret_cast<unsigned short*>(&h);
}
__device__ __forceinline__ uint4 pack8(float v0, float v1, float v2, float v3,
                                       float v4, float v5, float v6, float v7) {
    uint4 pk;
    pk.x = f2bf(v0) | (f2bf(v1) << 16);
    pk.y = f2bf(v2) | (f2bf(v3) << 16);
    pk.z = f2bf(v4) | (f2bf(v5) << 16);
    pk.w = f2bf(v6) | (f2bf(v7) << 16);
    return pk;
}
__device__ __forceinline__ void pair_decode(int mode, int p, int& pi, int& pj) {
    if (mode == 0) { int r = p, i = 0; while (r >= Nn - i) { r -= Nn - i; ++i; } pi = i; pj = i + r; }
    else { pi = p; pj = Zi; }
}
// async global->LDS, 16B/lane; dst must be wave-uniform base (+lane*16 by HW)
__device__ __forceinline__ void gl_lds16(const void* src, void* dst) {
    __builtin_amdgcn_global_load_lds((const __attribute__((address_space(1))) void*)src,
                                     (__attribute__((address_space(3))) void*)dst, 16, 0, 0);
}

// ---------------------------------------------------------------------------
__global__ void init_col_kernel(const float* __restrict__ nf, float* __restrict__ col) {
    int idx = blockIdx.x * 256 + threadIdx.x;
    int b = idx >> 9, f = idx & 511;
    col[idx] = nf[(b * Nn + Zi) * Ff + f];
}

// ---------------------------------------------------------------------------
// pack fp32 W[g][k] -> bf16 kq-plane-major chunks:
//   dstChunk[((g>>lgBW)*64 + kq) << lgBW | (g & (BW-1))] = bf16(W[g][kq*8..+8])
// Staged K-slices become fully contiguous (coalesced gl_lds).
// ---------------------------------------------------------------------------
__global__ void pack_w_kernel(const float* __restrict__ src,
                              unsigned short* __restrict__ dst, int lgBW) {
    int idx = blockIdx.x * 256 + threadIdx.x;   // total G*64 chunks
    int g = idx >> 6, kq = idx & 63;
    int nb = g >> lgBW, gl = g & ((1 << lgBW) - 1);
    const float* s = src + g * Ff + kq * 8;
    float4 a = *(const float4*)s, b = *(const float4*)(s + 4);
    uint4 pk = pack8(a.x, a.y, a.z, a.w, b.x, b.y, b.z, b.w);
    long long dc = (((long long)(nb << 6) + kq) << lgBW) + gl;
    *(uint4*)((char*)dst + dc * 16) = pk;
}

// ---------------------------------------------------------------------------
// Fused link MLP. Block = 32 rows (1 pair x 32 batches) x 512 cols, 512 thr,
// 8 waves, wave tile 32x64 (acc0+acc1 = 32 VGPR). K_STEP = 16.
// E resident: 64 planes x 32 rows x 16B (32 KB), built up-front; h1 in-place.
// W: packed kq-major -> each staged 16KB slice is CONTIGUOUS, gl_lds, dbuf.
// ~66 KB LDS -> 2 blocks/CU; one barrier per step.
// ---------------------------------------------------------------------------
__global__ __launch_bounds__(512, 4) void link_kernel(
    const float* __restrict__ nf, const float* __restrict__ colp,
    const unsigned short* __restrict__ W1p, const float* __restrict__ b1,
    const unsigned short* __restrict__ W2p, const float* __restrict__ b2,
    const float* __restrict__ w_out, const float* __restrict__ b_out,
    float* __restrict__ adj, int mode)
{
    __shared__ __align__(16) char Eb[64 * 32 * 16];      // 32,768 B
    __shared__ __align__(16) char Wb[2][2 * 512 * 16];   // 2 x 16,384 B
    __shared__ float Pl[8][32];

    const int tid = threadIdx.x;
    const int pr  = blockIdx.x >> 5;
    const int bc  = blockIdx.x & 31;
    int pi, pj; pair_decode(mode, pr, pi, pj);

    const int wid = tid >> 6;
    const int l   = tid & 63;
    const int lr  = l & 31;
    const int kg  = l >> 5;

    // ---- stage W1 slice 0 (contiguous 16 KB, async, no regs) ----
#pragma unroll
    for (int i = 0; i < 2; ++i) {
        int cb = i * 512 + wid * 64;           // wave-uniform chunk base
        gl_lds16(W1p + (cb + l) * 8, (char*)Wb[0] + cb * 16);
    }

    // ---- E build: row = tid>>4, 32 k per thread (coalesced 128B reads) ----
    {
        const int row = tid >> 4;
        const int kc  = tid & 15;
        const int b   = bc * 32 + row;
        const float* xi = (pi == Zi) ? (colp + b * Ff) : (nf + (b * Nn + pi) * Ff);
        const float* xj = (pj == Zi) ? (colp + b * Ff) : (nf + (b * Nn + pj) * Ff);
#pragma unroll
        for (int i = 0; i < 4; ++i) {
            const int k0 = kc * 32 + i * 8;
            const int plane = k0 >> 3;
            float4 u0 = *(const float4*)(xi + k0), u1 = *(const float4*)(xi + k0 + 4);
            float4 v0 = *(const float4*)(xj + k0), v1 = *(const float4*)(xj + k0 + 4);
            *(uint4*)(&Eb[(plane * 32 + row) * 16]) =
                pack8(u0.x*v0.x, u0.y*v0.y, u0.z*v0.z, u0.w*v0.w,
                      u1.x*v1.x, u1.y*v1.y, u1.z*v1.z, u1.w*v1.w);
        }
    }
    __syncthreads();    // drains stage-0 vmcnt + E writes

    f32x16 acc0 = (f32x16)(0.f), acc1 = (f32x16)(0.f);
    const int c0 = wid * 64 + lr;
    const int c1 = c0 + 32;

#pragma unroll 1
    for (int gks = 0; gks < 64; ++gks) {
        const int cur = gks & 1;

        // issue next W slice (contiguous; async)
        if (gks < 63) {
            const unsigned short* Wsp = (gks >= 31) ? W2p : W1p;
            const int kq0 = (((gks + 1) & 31)) * 2;     // k-octet base of slice
#pragma unroll
            for (int i = 0; i < 2; ++i) {
                int cb = i * 512 + wid * 64;
                gl_lds16(Wsp + (kq0 * 512 + cb + l) * 8, (char*)Wb[cur ^ 1] + cb * 16);
            }
        }

        // MFMA for this step (K=16)
        {
            const int ks = gks & 31;
            bfrag a  = *(const bfrag*)(&Eb[((ks * 2 + kg) * 32 + lr) * 16]);
            const char* Wc = (const char*)Wb[cur];
            bfrag w0 = *(const bfrag*)(Wc + (kg * 512 + c0) * 16);
            bfrag w1 = *(const bfrag*)(Wc + (kg * 512 + c1) * 16);
            acc0 = __builtin_amdgcn_mfma_f32_32x32x16_bf16(a, w0, acc0, 0, 0, 0);
            acc1 = __builtin_amdgcn_mfma_f32_32x32x16_bf16(a, w1, acc1, 0, 0, 0);
        }

        // layer boundary: h1 = relu(acc+b1) -> Eb in place
        if (gks == 31) {
            __syncthreads();   // all waves' E reads complete
            float bv0 = b1[c0], bv1 = b1[c1];
#pragma unroll
            for (int reg = 0; reg < 16; ++reg) {
                int row = (reg & 3) + 8 * (reg >> 2) + 4 * kg;
                float v0h = fmaxf(acc0[reg] + bv0, 0.f);
                float v1h = fmaxf(acc1[reg] + bv1, 0.f);
                *(unsigned short*)(&Eb[((c0 >> 3) * 32 + row) * 16 + (c0 & 7) * 2]) =
                    (unsigned short)f2bf(v0h);
                *(unsigned short*)(&Eb[((c1 >> 3) * 32 + row) * 16 + (c1 & 7) * 2]) =
                    (unsigned short)f2bf(v1h);
            }
            acc0 = (f32x16)(0.f);
            acc1 = (f32x16)(0.f);
        }

        __syncthreads();   // next slice staged + h1/reads published
    }

    // ---- fused layer-3: rowsum of relu(acc+b2)*w_out ----
    {
        float bv0 = b2[c0], bv1 = b2[c1];
        float wv0 = w_out[c0], wv1 = w_out[c1];
        float rs[16];
#pragma unroll
        for (int reg = 0; reg < 16; ++reg)
            rs[reg] = fmaxf(acc0[reg] + bv0, 0.f) * wv0
                    + fmaxf(acc1[reg] + bv1, 0.f) * wv1;
#pragma unroll
        for (int off = 1; off < 32; off <<= 1)
#pragma unroll
            for (int reg = 0; reg < 16; ++reg)
                rs[reg] += __shfl_xor(rs[reg], off);
        if (lr == 0) {
#pragma unroll
            for (int reg = 0; reg < 16; ++reg) {
                int row = (reg & 3) + 8 * (reg >> 2) + 4 * kg;
                Pl[wid][row] = rs[reg];
            }
        }
    }
    __syncthreads();
    if (tid < 32) {
        float v = b_out[0];
#pragma unroll
        for (int w = 0; w < 8; ++w) v += Pl[w][tid];
        int b = bc * 32 + tid;
        adj[b * (Nn * Nn) + pi * Nn + pj] = v;
        if (pi != pj) adj[b * (Nn * Nn) + pj * Nn + pi] = v;
    }
}

// ---------------------------------------------------------------------------
__global__ void softmax_az_kernel(const float* __restrict__ adj, float* __restrict__ a_z) {
    int b = blockIdx.x * 256 + threadIdx.x;
    if (b >= Bsz) return;
    const float* row = adj + b * (Nn * Nn) + Zi * Nn;
    float mx = row[0];
#pragma unroll
    for (int j = 1; j < Nn; ++j) mx = fmaxf(mx, row[j]);
    float e[Nn]; float s = 0.f;
#pragma unroll
    for (int j = 0; j < Nn; ++j) { e[j] = expf(row[j] - mx); s += e[j]; }
    float inv = 1.f / s;
#pragma unroll
    for (int j = 0; j < Nn; ++j) a_z[b * Nn + j] = e[j] * inv;
}

__global__ void mfix_kernel(const float* __restrict__ nf, const float* __restrict__ a_z,
                            float* __restrict__ m_fix) {
    int idx = blockIdx.x * 256 + threadIdx.x;
    int b = idx >> 9, f = idx & 511;
    float s = 0.f;
#pragma unroll
    for (int j = 0; j < Nn - 1; ++j)
        s += a_z[b * Nn + j] * nf[(b * Nn + j) * Ff + f];
    m_fix[idx] = s;
}

// ---------------------------------------------------------------------------
// gates: gi = (m_fix + az*col) @ Wih^T ; gh = col @ Whh^T (fp32 out)
// Block: 256 thr, 4 waves, tile 64 x 128, K_STEP=32. W staged via gl_lds from
// packed layout (contiguous 2KB planes); A reg-staged dbuf (fp32->bf16).
// ---------------------------------------------------------------------------
__global__ __launch_bounds__(256, 3) void gates_kernel(
    const float* __restrict__ m_fix, const float* __restrict__ a_z,
    const float* __restrict__ colp,
    const unsigned short* __restrict__ Wihp, const unsigned short* __restrict__ Whhp,
    float* __restrict__ gi, float* __restrict__ gh)
{
    __shared__ __align__(16) char Wb[2][4 * 128 * 16];   // 2 x 8,192 B
    __shared__ __align__(16) char Ab[2][4 * 64 * 16];    // 2 x 4,096 B

    const int xb = blockIdx.x, bc = blockIdx.y, tid = threadIdx.x;
    const bool isGi = xb < 12;
    const int nb = isGi ? xb : xb - 12;
    const unsigned short* Wp = isGi ? Wihp : Whhp;
    float* C = isGi ? gi : gh;

    const int wid = tid >> 6;
    const int l   = tid & 63;
    const int bloc = tid >> 2;
    const int kc   = tid & 3;
    const int b    = bc * 64 + bloc;
    const float* cs = colp + b * Ff;
    const float* mf = m_fix + b * Ff;
    const float azv = isGi ? a_z[b * Nn + Zi] : 0.f;

    uint4 areg;
    auto loadA = [&](int k0) {
        const float* pc = cs + k0 + kc * 8;
        float4 c0 = *(const float4*)pc, c1 = *(const float4*)(pc + 4);
        if (isGi) {
            const float* pm = mf + k0 + kc * 8;
            float4 m0 = *(const float4*)pm, m1 = *(const float4*)(pm + 4);
            areg = pack8(m0.x + azv*c0.x, m0.y + azv*c0.y, m0.z + azv*c0.z, m0.w + azv*c0.w,
                         m1.x + azv*c1.x, m1.y + azv*c1.y, m1.z + azv*c1.z, m1.w + azv*c1.w);
        } else {
            areg = pack8(c0.x, c0.y, c0.z, c0.w, c1.x, c1.y, c1.z, c1.w);
        }
    };
    // stage W K-slice (4 planes x 128 chunks = 8 KB contiguous), async
    auto stageW = [&](int ks, int buf) {
        const int base = nb * 8192 + ks * 4 * 128;   // chunk index of slice
#pragma unroll
        for (int i = 0; i < 2; ++i) {
            int cb = i * 256 + wid * 64;
            gl_lds16(Wp + (base + cb + l) * 8, (char*)Wb[buf] + cb * 16);
        }
    };

    stageW(0, 0);
    loadA(0);
    *(uint4*)(&Ab[0][(kc * 64 + bloc) * 16]) = areg;
    __syncthreads();

    const int lr = l & 31;
    const int kg = l >> 5;

    f32x16 acc[2];
    acc[0] = (f32x16)(0.f);
    acc[1] = (f32x16)(0.f);

#pragma unroll 1
    for (int ks = 0; ks < 16; ++ks) {
        const int cur = ks & 1;
        if (ks < 15) {
            stageW(ks + 1, cur ^ 1);
            loadA((ks + 1) * 32);
        }
#pragma unroll
        for (int s = 0; s < 2; ++s) {
            const int kcv = 2 * s + kg;
            bfrag a0 = *(const bfrag*)(&Ab[cur][(kcv * 64 + lr) * 16]);
            bfrag a1 = *(const bfrag*)(&Ab[cur][(kcv * 64 + 32 + lr) * 16]);
            bfrag bf = *(const bfrag*)(&Wb[cur][(kcv * 128 + wid * 32 + lr) * 16]);
            acc[0] = __builtin_amdgcn_mfma_f32_32x32x16_bf16(a0, bf, acc[0], 0, 0, 0);
            acc[1] = __builtin_amdgcn_mfma_f32_32x32x16_bf16(a1, bf, acc[1], 0, 0, 0);
        }
        if (ks < 15)
            *(uint4*)(&Ab[cur ^ 1][(kc * 64 + bloc) * 16]) = areg;
        __syncthreads();
    }

    const int colg = nb * 128 + wid * 32 + lr;
#pragma unroll
    for (int m = 0; m < 2; ++m) {
#pragma unroll
        for (int reg = 0; reg < 16; ++reg) {
            int row = m * 32 + (reg & 3) + 8 * (reg >> 2) + 4 * kg;
            C[(bc * 64 + row) * G3 + colg] = acc[m][reg];
        }
    }
}

// ---------------------------------------------------------------------------
__global__ void gru_kernel(const float* __restrict__ gi, const float* __restrict__ gh,
                           float* __restrict__ col) {
    int idx = blockIdx.x * 256 + threadIdx.x;   // 4 f per thread
    int b = idx >> 7, f = (idx & 127) * 4;
    const float* gib = gi + b * G3;
    const float* ghb = gh + b * G3;
    float4 ir = *(const float4*)(gib + f);
    float4 iz = *(const float4*)(gib + Ff + f);
    float4 in = *(const float4*)(gib + 2 * Ff + f);
    float4 hr = *(const float4*)(ghb + f);
    float4 hz = *(const float4*)(ghb + Ff + f);
    float4 hn = *(const float4*)(ghb + 2 * Ff + f);
    float4 h  = *(const float4*)(col + b * Ff + f);
    float4 o;
#define GRU1(c) { \
    float r = 1.f / (1.f + expf(-(ir.c + hr.c))); \
    float z = 1.f / (1.f + expf(-(iz.c + hz.c))); \
    float n = tanhf(in.c + r * hn.c); \
    o.c = (1.f - z) * n + z * h.c; }
    GRU1(x) GRU1(y) GRU1(z) GRU1(w)
#undef GRU1
    *(float4*)(col + b * Ff + f) = o;
}

// ---------------------------------------------------------------------------
extern "C" void kernel_launch(void* const* d_in, const int* in_sizes, int n_in,
                              void* d_out, int out_size, void* d_ws, size_t ws_size,
                              hipStream_t stream) {
    const float* nf    = (const float*)d_in[0];
    const float* W1    = (const float*)d_in[1];
    const float* b1    = (const float*)d_in[2];
    const float* W2    = (const float*)d_in[3];
    const float* b2    = (const float*)d_in[4];
    const float* w_out = (const float*)d_in[5];
    const float* b_out = (const float*)d_in[6];
    const float* W_ih  = (const float*)d_in[7];
    const float* W_hh  = (const float*)d_in[8];

    float* adj = (float*)d_out;                 // (B, 11, 11)
    float* col = adj + Bsz * Nn * Nn;           // (B, 512)

    unsigned short* W1p  = (unsigned short*)d_ws;        // packed, 512*512
    unsigned short* W2p  = W1p + Ff * Ff;
    unsigned short* Wihp = W2p + Ff * Ff;                // packed, 1536*512
    unsigned short* Whhp = Wihp + G3 * Ff;
    float* a_z   = (float*)(Whhp + G3 * Ff);
    float* m_fix = a_z + 16384;
    float* gi    = m_fix + Bsz * Ff;
    float* gh    = gi + Bsz * G3;

    init_col_kernel<<<(Bsz * Ff) / 256, 256, 0, stream>>>(nf, col);
    pack_w_kernel<<<(Ff * 64) / 256, 256, 0, stream>>>(W1, W1p, 9);
    pack_w_kernel<<<(Ff * 64) / 256, 256, 0, stream>>>(W2, W2p, 9);
    pack_w_kernel<<<(G3 * 64) / 256, 256, 0, stream>>>(W_ih, Wihp, 7);
    pack_w_kernel<<<(G3 * 64) / 256, 256, 0, stream>>>(W_hh, Whhp, 7);

    for (int t = 0; t < 3; ++t) {
        const int mode   = (t == 0) ? 0 : 1;
        const int npairs = (t == 0) ? 66 : 11;

        link_kernel<<<npairs * 32, 512, 0, stream>>>(nf, col, W1p, b1, W2p, b2,
                                                     w_out, b_out, adj, mode);
        softmax_az_kernel<<<Bsz / 256, 256, 0, stream>>>(adj, a_z);
        mfix_kernel<<<(Bsz * Ff) / 256, 256, 0, stream>>>(nf, a_z, m_fix);

        for (int s = 0; s < 3; ++s) {
            gates_kernel<<<dim3(24, 16), 256, 0, stream>>>(m_fix, a_z, col,
                                                           Wihp, Whhp, gi, gh);
            gru_kernel<<<(Bsz * Ff) / 4 / 256, 256, 0, stream>>>(gi, gh, col);
        }
    }
}